// Round 1
// baseline (447.788 us; speedup 1.0000x reference)
//
#include <hip/hip_runtime.h>

// KV cache scatter update:
//   kout = k_cache; kout[:, :, pos_ids, :] = k   (same for v)
// Shapes: cache (1, 8, 32768, 128) f32 = 128 MiB each; k/v (1, 8, 2048, 128) f32.
// Output = [kout flat | vout flat], 256 MiB total. Memory-bound; floor ~86us @6.3TB/s.

constexpr long N_KV     = 8;
constexpr long MAX_CTX  = 32768;
constexpr long HEAD_DIM = 128;
constexpr long CHUNK    = 2048;

constexpr long CACHE_ELEMS = N_KV * MAX_CTX * HEAD_DIM;   // 33,554,432 floats
constexpr long CACHE_N4    = CACHE_ELEMS / 4;             // 8,388,608 float4
constexpr long KV_ELEMS    = N_KV * CHUNK * HEAD_DIM;     // 2,097,152 floats
constexpr long KV_N4       = KV_ELEMS / 4;                // 524,288 float4
constexpr long C4          = HEAD_DIM / 4;                // 32 float4 per row

// Kernel 1: copy both caches into the two output halves. 16B/lane coalesced.
__global__ void kv_copy_kernel(const float4* __restrict__ kc,
                               const float4* __restrict__ vc,
                               float4* __restrict__ out_k,
                               float4* __restrict__ out_v) {
    long i      = (long)blockIdx.x * blockDim.x + threadIdx.x;
    long stride = (long)gridDim.x * blockDim.x;
    for (; i < CACHE_N4; i += stride) {
        out_k[i] = kc[i];
        out_v[i] = vc[i];
    }
}

// Kernel 2: scatter new k/v rows into the output caches at pos_ids.
// Each thread moves one float4 of k and the matching float4 of v.
__global__ void kv_scatter_kernel(const float4* __restrict__ k,
                                  const float4* __restrict__ v,
                                  const int* __restrict__ pos,
                                  float4* __restrict__ out_k,
                                  float4* __restrict__ out_v) {
    long i      = (long)blockIdx.x * blockDim.x + threadIdx.x;
    long stride = (long)gridDim.x * blockDim.x;
    for (; i < KV_N4; i += stride) {
        long col = i & (C4 - 1);          // float4 column within the 128-dim row
        long r   = i / C4;                // flat (head, chunk_row)
        long row = r & (CHUNK - 1);       // chunk row -> index into pos_ids
        long h   = r / CHUNK;             // kv head
        long p   = (long)pos[row];        // destination context position
        long o   = (h * MAX_CTX + p) * C4 + col;
        out_k[o] = k[i];
        out_v[o] = v[i];
    }
}

extern "C" void kernel_launch(void* const* d_in, const int* in_sizes, int n_in,
                              void* d_out, int out_size, void* d_ws, size_t ws_size,
                              hipStream_t stream) {
    const float4* k_cache = (const float4*)d_in[0];
    const float4* v_cache = (const float4*)d_in[1];
    const int*    pos     = (const int*)  d_in[2];
    const float4* k       = (const float4*)d_in[3];
    const float4* v       = (const float4*)d_in[4];

    float* out   = (float*)d_out;
    float4* out_k = (float4*)out;
    float4* out_v = (float4*)(out + CACHE_ELEMS);

    // Copy: 8.39M float4 per cache; 256 thr/blk, each thread does one k + one v float4.
    {
        int block = 256;
        long want = (CACHE_N4 + block - 1) / block;     // 32768 blocks
        int grid  = (int)(want > 32768 ? 32768 : want);
        kv_copy_kernel<<<grid, block, 0, stream>>>(k_cache, v_cache, out_k, out_v);
    }
    // Scatter: 524288 float4 -> 2048 blocks. Must run after (same stream ordering).
    {
        int block = 256;
        int grid  = (int)((KV_N4 + block - 1) / block); // 2048 blocks
        kv_scatter_kernel<<<grid, block, 0, stream>>>(k, v, pos, out_k, out_v);
    }
}